// Round 1
// baseline (464.190 us; speedup 1.0000x reference)
//
#include <hip/hip_runtime.h>

// ---------------- problem constants ----------------
constexpr int NN   = 20000;   // nodes
constexpr int NE   = 160000;  // edges
constexpr int NG   = 32;      // graphs
constexpr int IN   = 27;
constexpr int HID  = 512;
constexpr int OUT  = 256;
constexpr int MPAD = 20096;   // 157 * 128
constexpr int MT   = MPAD / 128; // 157 m-tiles

typedef unsigned short u16;
typedef __bf16 bf16x8 __attribute__((ext_vector_type(8)));
typedef float  f32x4  __attribute__((ext_vector_type(4)));
typedef u16    u16x4  __attribute__((ext_vector_type(4)));

__device__ __forceinline__ u16 f2b(float x) {
  __bf16 h = (__bf16)x;                 // RNE convert
  return __builtin_bit_cast(u16, h);
}
__device__ __forceinline__ float b2f(u16 u) {
  __bf16 h = __builtin_bit_cast(__bf16, u);
  return (float)h;
}

#define GLOBAL_AS __attribute__((address_space(1)))
#define LDS_AS    __attribute__((address_space(3)))
__device__ __forceinline__ void gload_lds16(const void* g, void* l) {
  __builtin_amdgcn_global_load_lds((const GLOBAL_AS void*)g, (LDS_AS void*)l, 16, 0, 0);
}

// ---------------- CSR build ----------------
__global__ void k_deg(const int* __restrict__ dst, int* __restrict__ deg) {
  int e = blockIdx.x * 256 + threadIdx.x;
  if (e < NE) atomicAdd(&deg[dst[e]], 1);
}

// single-block iterative scan: rowptr (exclusive), cursor copy, inv_deg
__global__ void k_scan(const int* __restrict__ deg, int* __restrict__ rowptr,
                       int* __restrict__ cursor, float* __restrict__ invdeg) {
  __shared__ int sd[1024];
  __shared__ int s_base;
  const int tid = threadIdx.x;
  if (tid == 0) s_base = 0;
  __syncthreads();
  for (int base = 0; base < NN; base += 1024) {
    const int i = base + tid;
    const int d = (i < NN) ? deg[i] : 0;
    sd[tid] = d;
    __syncthreads();
    for (int off = 1; off < 1024; off <<= 1) {
      int t = (tid >= off) ? sd[tid - off] : 0;
      __syncthreads();
      sd[tid] += t;
      __syncthreads();
    }
    const int incl  = sd[tid];
    const int total = s_base;
    if (i < NN) {
      const int excl = total + incl - d;
      rowptr[i] = excl;
      cursor[i] = excl;
      invdeg[i] = 1.0f / fmaxf((float)d, 1.0f);
    }
    __syncthreads();
    if (tid == 1023) s_base = total + sd[1023];
    __syncthreads();
  }
  if (tid == 0) rowptr[NN] = s_base;
}

__global__ void k_scatter(const int* __restrict__ src, const int* __restrict__ dst,
                          int* __restrict__ cursor, int* __restrict__ ssrc) {
  int e = blockIdx.x * 256 + threadIdx.x;
  if (e < NE) {
    int p = atomicAdd(&cursor[dst[e]], 1);
    ssrc[p] = src[e];
  }
}

// ---------------- weight convert: fp32 [K][Nout] (+optional second) -> bf16 B^T [Nout][Kpad]
__global__ void k_wconv(const float* __restrict__ W1, int K1,
                        const float* __restrict__ W2, int K2,
                        int Kpad, int Nout, u16* __restrict__ Bt) {
  int idx = blockIdx.x * 256 + threadIdx.x;
  if (idx >= Nout * Kpad) return;
  int n = idx / Kpad, k = idx % Kpad;
  float v = 0.0f;
  if (k < K1)            v = W1[(size_t)k * Nout + n];
  else if (k < K1 + K2)  v = W2[(size_t)(k - K1) * Nout + n];
  Bt[idx] = f2b(v);
}

// ---------------- A0 = [bf16(feature) | bf16(mean-agg(feature)) | zeros], [MPAD][64]
__global__ void k_build_A0(const float* __restrict__ feat, const int* __restrict__ rowptr,
                           const int* __restrict__ ssrc, const float* __restrict__ invdeg,
                           u16* __restrict__ A0) {
  const int r = blockIdx.x, t = threadIdx.x; // 64 threads
  u16* row = A0 + (size_t)r * 64;
  if (r >= NN) { row[t] = 0; return; }
  if (t < IN) {
    row[t] = f2b(feat[(size_t)r * IN + t]);
    float s = 0.0f;
    const int e0 = rowptr[r], e1 = rowptr[r + 1];
    for (int e = e0; e < e1; ++e) s += feat[(size_t)ssrc[e] * IN + t];
    row[IN + t] = f2b(s * invdeg[r]);
  } else if (t >= 2 * IN) {
    row[t] = 0;
  }
}

// ---------------- agg over 512 bf16 cols of A1 (h0 half) -> A1 cols 512..1023
__global__ void k_agg512(u16* __restrict__ A1, const int* __restrict__ rowptr,
                         const int* __restrict__ ssrc, const float* __restrict__ invdeg) {
  const int r = blockIdx.x, t = threadIdx.x; // 128 threads, 4 cols each
  float a0 = 0, a1 = 0, a2 = 0, a3 = 0;
  const int e0 = rowptr[r], e1 = rowptr[r + 1];
  for (int e = e0; e < e1; ++e) {
    const u16x4 v = *(const u16x4*)(A1 + (size_t)ssrc[e] * 1024 + t * 4);
    a0 += b2f(v.x); a1 += b2f(v.y); a2 += b2f(v.z); a3 += b2f(v.w);
  }
  const float inv = invdeg[r];
  u16x4 o; o.x = f2b(a0 * inv); o.y = f2b(a1 * inv); o.z = f2b(a2 * inv); o.w = f2b(a3 * inv);
  *(u16x4*)(A1 + (size_t)r * 1024 + 512 + t * 4) = o;
}

// ---------------- agg over 256 bf16 cols of T2 -> AGG2 fp32 [NN][256]
__global__ void k_agg256(const u16* __restrict__ T2, const int* __restrict__ rowptr,
                         const int* __restrict__ ssrc, const float* __restrict__ invdeg,
                         float* __restrict__ AGG2) {
  const int r = blockIdx.x, t = threadIdx.x; // 64 threads, 4 cols each
  float a0 = 0, a1 = 0, a2 = 0, a3 = 0;
  const int e0 = rowptr[r], e1 = rowptr[r + 1];
  for (int e = e0; e < e1; ++e) {
    const u16x4 v = *(const u16x4*)(T2 + (size_t)ssrc[e] * 256 + t * 4);
    a0 += b2f(v.x); a1 += b2f(v.y); a2 += b2f(v.z); a3 += b2f(v.w);
  }
  const float inv = invdeg[r];
  f32x4 o = {a0 * inv, a1 * inv, a2 * inv, a3 * inv};
  *(f32x4*)(AGG2 + (size_t)r * 256 + t * 4) = o;
}

// ---------------- MFMA GEMM: D = A[MPAD][lda](bf16) x Bt[Nout][K](bf16)^T tiles 128x128
// flags: 1 = relu (bf16 out), 2 = fp32 out to d_out with row<NN guard (+addp)
__global__ __launch_bounds__(256) void k_gemm(
    const u16* __restrict__ A, int lda,
    const u16* __restrict__ Bt, int K,
    void* __restrict__ Out, int ldo,
    const float* __restrict__ bias,
    const float* __restrict__ addp,
    int flags) {
  __shared__ u16 As[128 * 64];
  __shared__ u16 Bs[128 * 64];
  const int tid = threadIdx.x;
  const int wid = tid >> 6, lane = tid & 63;
  const int l16 = lane & 15, lhi = lane >> 4;
  const int wr = wid >> 1, wc = wid & 1;
  const int row0 = blockIdx.x * 128, col0 = blockIdx.y * 128;

  // staging decomposition: each thread owns one 16B slot; swizzle the GLOBAL
  // source slot so a swizzled ds_read_b128 sees linear data (rule 21)
  const int tr    = tid >> 3;              // row within 32-row issue
  const int slot  = tid & 7;               // 16B slot within 128B row
  const int sslot = slot ^ (tr & 7);       // inverse-swizzled source slot

  f32x4 acc[4][4] = {};

  for (int kt = 0; kt < K; kt += 64) {
#pragma unroll
    for (int i = 0; i < 4; ++i) {
      const int r = i * 32 + tr;
      gload_lds16(A  + (size_t)(row0 + r) * lda + kt + sslot * 8, &As[i * 2048 + wid * 512]);
      gload_lds16(Bt + (size_t)(col0 + r) * K   + kt + sslot * 8, &Bs[i * 2048 + wid * 512]);
    }
    __syncthreads();
#pragma unroll
    for (int ks = 0; ks < 2; ++ks) {
      bf16x8 af[4], bfr[4];
#pragma unroll
      for (int i = 0; i < 4; ++i) {
        const int r = wr * 64 + i * 16 + l16;
        const int s = (ks * 4 + lhi) ^ (r & 7);
        af[i] = *(const bf16x8*)&As[r * 64 + s * 8];
      }
#pragma unroll
      for (int n = 0; n < 4; ++n) {
        const int c = wc * 64 + n * 16 + l16;
        const int s = (ks * 4 + lhi) ^ (c & 7);
        bfr[n] = *(const bf16x8*)&Bs[c * 64 + s * 8];
      }
#pragma unroll
      for (int i = 0; i < 4; ++i)
#pragma unroll
        for (int n = 0; n < 4; ++n)
          acc[i][n] = __builtin_amdgcn_mfma_f32_16x16x32_bf16(af[i], bfr[n], acc[i][n], 0, 0, 0);
    }
    __syncthreads();
  }

  const bool relu = flags & 1;
  const bool f32o = flags & 2;
#pragma unroll
  for (int i = 0; i < 4; ++i) {
#pragma unroll
    for (int n = 0; n < 4; ++n) {
      const int C = col0 + wc * 64 + n * 16 + l16;
      const float bv = bias ? bias[C] : 0.0f;
#pragma unroll
      for (int q = 0; q < 4; ++q) {
        const int R = row0 + wr * 64 + i * 16 + lhi * 4 + q;
        float v = acc[i][n][q] + bv;
        if (f32o) {
          if (R < NN) {
            if (addp) v += addp[(size_t)R * ldo + C];
            ((float*)Out)[(size_t)R * ldo + C] = v;
          }
        } else {
          if (relu) v = fmaxf(v, 0.0f);
          ((u16*)Out)[(size_t)R * ldo + C] = f2b(v);
        }
      }
    }
  }
}

// ---------------- pooling ----------------
__global__ void k_ghist(const int* __restrict__ gid, int* __restrict__ gcount) {
  int i = blockIdx.x * 256 + threadIdx.x;
  if (i < NN) atomicAdd(&gcount[gid[i]], 1);
}
__global__ void k_gscan(const int* __restrict__ gcount, int* __restrict__ gstart) {
  if (threadIdx.x == 0) {
    int s = 0;
    for (int g = 0; g < NG; ++g) { gstart[g] = s; s += gcount[g]; }
    gstart[NG] = s;
  }
}
__global__ void k_pool(const float* __restrict__ h, const int* __restrict__ gstart,
                       float* __restrict__ hg) {
  const int g = blockIdx.x >> 3, s = blockIdx.x & 7;
  const int t = threadIdx.x; // 256 = output col
  const int n0 = gstart[g], n1 = gstart[g + 1];
  const int len = n1 - n0, chunk = (len + 7) / 8;
  const int a = n0 + s * chunk;
  const int b = min(a + chunk, n1);
  float acc = 0.0f;
  for (int i = a; i < b; ++i) acc += h[(size_t)i * 256 + t];
  if (b > a) atomicAdd(&hg[g * 256 + t], acc);
}
__global__ void k_pooldiv(float* __restrict__ hg, const int* __restrict__ gcount) {
  const int g = blockIdx.x, t = threadIdx.x;
  hg[g * 256 + t] /= fmaxf((float)gcount[g], 1.0f);
}

// ---------------- workspace layout (bytes) ----------------
constexpr size_t OFF_A0    = 0;                                   // [MPAD][64] bf16
constexpr size_t OFF_A1    = OFF_A0   + (size_t)MPAD * 64  * 2;   // [MPAD][1024] bf16 (h0|agg1)
constexpr size_t OFF_H1    = OFF_A1   + (size_t)MPAD * 1024 * 2;  // [MPAD][512] bf16
constexpr size_t OFF_T2    = OFF_H1   + (size_t)MPAD * 512 * 2;   // [MPAD][256] bf16
constexpr size_t OFF_AGG2  = OFF_T2   + (size_t)MPAD * 256 * 2;   // [NN][256] fp32
constexpr size_t OFF_BT0   = OFF_AGG2 + (size_t)NN * 256 * 4;     // [512][64] bf16
constexpr size_t OFF_BT1   = OFF_BT0  + (size_t)512 * 64 * 2;     // [512][1024] bf16
constexpr size_t OFF_BTS2  = OFF_BT1  + (size_t)512 * 1024 * 2;   // [256][512] bf16
constexpr size_t OFF_BTN2  = OFF_BTS2 + (size_t)256 * 512 * 2;    // [256][512] bf16
constexpr size_t OFF_DEG   = OFF_BTN2 + (size_t)256 * 512 * 2;    // [NN] int
constexpr size_t OFF_RP    = OFF_DEG  + (size_t)NN * 4;           // [NN+1] int
constexpr size_t OFF_CUR   = OFF_RP   + (size_t)(NN + 2) * 4;     // [NN] int
constexpr size_t OFF_SSRC  = OFF_CUR  + (size_t)NN * 4;           // [NE] int
constexpr size_t OFF_INVD  = OFF_SSRC + (size_t)NE * 4;           // [NN] float
constexpr size_t OFF_GCNT  = OFF_INVD + (size_t)NN * 4;           // [NG] int
constexpr size_t OFF_GST   = OFF_GCNT + (size_t)NG * 4;           // [NG+1] int

extern "C" void kernel_launch(void* const* d_in, const int* in_sizes, int n_in,
                              void* d_out, int out_size, void* d_ws, size_t ws_size,
                              hipStream_t stream) {
  const float* feature = (const float*)d_in[0];
  const int*   esrc    = (const int*)d_in[1];
  const int*   edst    = (const int*)d_in[2];
  const int*   gid     = (const int*)d_in[3];
  const float* Ws0 = (const float*)d_in[4],  *Wn0 = (const float*)d_in[5],  *b0 = (const float*)d_in[6];
  const float* Ws1 = (const float*)d_in[7],  *Wn1 = (const float*)d_in[8],  *b1 = (const float*)d_in[9];
  const float* Ws2 = (const float*)d_in[10], *Wn2 = (const float*)d_in[11], *b2 = (const float*)d_in[12];

  char* ws = (char*)d_ws;
  u16*   A0    = (u16*)  (ws + OFF_A0);
  u16*   A1    = (u16*)  (ws + OFF_A1);
  u16*   H1    = (u16*)  (ws + OFF_H1);
  u16*   T2    = (u16*)  (ws + OFF_T2);
  float* AGG2  = (float*)(ws + OFF_AGG2);
  u16*   Bt0   = (u16*)  (ws + OFF_BT0);
  u16*   Bt1   = (u16*)  (ws + OFF_BT1);
  u16*   BtS2  = (u16*)  (ws + OFF_BTS2);
  u16*   BtN2  = (u16*)  (ws + OFF_BTN2);
  int*   deg   = (int*)  (ws + OFF_DEG);
  int*   rp    = (int*)  (ws + OFF_RP);
  int*   cur   = (int*)  (ws + OFF_CUR);
  int*   ssrc  = (int*)  (ws + OFF_SSRC);
  float* invd  = (float*)(ws + OFF_INVD);
  int*   gcnt  = (int*)  (ws + OFF_GCNT);
  int*   gst   = (int*)  (ws + OFF_GST);

  float* out_h  = (float*)d_out;
  float* out_hg = out_h + (size_t)NN * OUT;

  hipMemsetAsync(deg,  0, (size_t)NN * 4, stream);
  hipMemsetAsync(gcnt, 0, (size_t)NG * 4, stream);
  hipMemsetAsync(out_hg, 0, (size_t)NG * OUT * 4, stream);

  // CSR by dst
  k_deg    <<<(NE + 255) / 256, 256, 0, stream>>>(edst, deg);
  k_scan   <<<1, 1024, 0, stream>>>(deg, rp, cur, invd);
  k_scatter<<<(NE + 255) / 256, 256, 0, stream>>>(esrc, edst, cur, ssrc);

  // weights -> bf16 B^T
  k_wconv<<<(512 * 64   + 255) / 256, 256, 0, stream>>>(Ws0, IN,  Wn0, IN,  64,   512, Bt0);
  k_wconv<<<(512 * 1024 + 255) / 256, 256, 0, stream>>>(Ws1, HID, Wn1, HID, 1024, 512, Bt1);
  k_wconv<<<(256 * 512  + 255) / 256, 256, 0, stream>>>(Ws2, HID, nullptr, 0, 512, 256, BtS2);
  k_wconv<<<(256 * 512  + 255) / 256, 256, 0, stream>>>(Wn2, HID, nullptr, 0, 512, 256, BtN2);

  // layer 0: A0 = [f | agg(f)], h0 = relu(A0 @ [Ws0;Wn0] + b0) -> A1[:, :512]
  k_build_A0<<<MPAD, 64, 0, stream>>>(feature, rp, ssrc, invd, A0);
  k_gemm<<<dim3(MT, 4), 256, 0, stream>>>(A0, 64, Bt0, 64, A1, 1024, b0, nullptr, 1);

  // layer 1: agg1 -> A1[:, 512:], h1 = relu(A1 @ [Ws1;Wn1] + b1)
  k_agg512<<<NN, 128, 0, stream>>>(A1, rp, ssrc, invd);
  k_gemm<<<dim3(MT, 4), 256, 0, stream>>>(A1, 1024, Bt1, 1024, H1, 512, b1, nullptr, 1);

  // layer 2: t2 = h1 @ Wn2; agg2 = mean(t2); out = h1 @ Ws2 + agg2 + b2
  k_gemm<<<dim3(MT, 2), 256, 0, stream>>>(H1, 512, BtN2, 512, T2, 256, nullptr, nullptr, 0);
  k_agg256<<<NN, 64, 0, stream>>>(T2, rp, ssrc, invd, AGG2);
  k_gemm<<<dim3(MT, 2), 256, 0, stream>>>(H1, 512, BtS2, 512, out_h, 256, b2, AGG2, 2);

  // avg pooling per graph (graph_ids sorted)
  k_ghist  <<<(NN + 255) / 256, 256, 0, stream>>>(gid, gcnt);
  k_gscan  <<<1, 32, 0, stream>>>(gcnt, gst);
  k_pool   <<<NG * 8, 256, 0, stream>>>(out_h, gst, out_hg);
  k_pooldiv<<<NG, 256, 0, stream>>>(out_hg, gcnt);
}

// Round 4
// 345.329 us; speedup vs baseline: 1.3442x; 1.3442x over previous
//
#include <hip/hip_runtime.h>

// ---------------- problem constants ----------------
constexpr int NN   = 20000;   // nodes
constexpr int NE   = 160000;  // edges
constexpr int NG   = 32;      // graphs
constexpr int IN   = 27;
constexpr int HID  = 512;
constexpr int OUT  = 256;
constexpr int MPAD = 20096;   // 157 * 128
constexpr int MT   = MPAD / 128; // 157 m-tiles

typedef unsigned short u16;
typedef __bf16 bf16x8 __attribute__((ext_vector_type(8)));
typedef float  f32x4  __attribute__((ext_vector_type(4)));
typedef u16    u16x4  __attribute__((ext_vector_type(4)));

__device__ __forceinline__ u16 f2b(float x) {
  __bf16 h = (__bf16)x;                 // RNE convert
  return __builtin_bit_cast(u16, h);
}
__device__ __forceinline__ float b2f(u16 u) {
  __bf16 h = __builtin_bit_cast(__bf16, u);
  return (float)h;
}

#define GLOBAL_AS __attribute__((address_space(1)))
#define LDS_AS    __attribute__((address_space(3)))
__device__ __forceinline__ void gload_lds16(const void* g, void* l) {
  __builtin_amdgcn_global_load_lds((const GLOBAL_AS void*)g, (LDS_AS void*)l, 16, 0, 0);
}

// ---------------- CSR build ----------------
__global__ void k_deg(const int* __restrict__ dst, int* __restrict__ deg) {
  int e = blockIdx.x * 256 + threadIdx.x;
  if (e < NE) atomicAdd(&deg[dst[e]], 1);
}

// single-block iterative scan: rowptr (exclusive), cursor copy, inv_deg
__global__ void k_scan(const int* __restrict__ deg, int* __restrict__ rowptr,
                       int* __restrict__ cursor, float* __restrict__ invdeg) {
  __shared__ int sd[1024];
  __shared__ int s_base;
  const int tid = threadIdx.x;
  if (tid == 0) s_base = 0;
  __syncthreads();
  for (int base = 0; base < NN; base += 1024) {
    const int i = base + tid;
    const int d = (i < NN) ? deg[i] : 0;
    sd[tid] = d;
    __syncthreads();
    for (int off = 1; off < 1024; off <<= 1) {
      int t = (tid >= off) ? sd[tid - off] : 0;
      __syncthreads();
      sd[tid] += t;
      __syncthreads();
    }
    const int incl  = sd[tid];
    const int total = s_base;
    if (i < NN) {
      const int excl = total + incl - d;
      rowptr[i] = excl;
      cursor[i] = excl;
      invdeg[i] = 1.0f / fmaxf((float)d, 1.0f);
    }
    __syncthreads();
    if (tid == 1023) s_base = total + sd[1023];
    __syncthreads();
  }
  if (tid == 0) rowptr[NN] = s_base;
}

__global__ void k_scatter(const int* __restrict__ src, const int* __restrict__ dst,
                          int* __restrict__ cursor, int* __restrict__ ssrc) {
  int e = blockIdx.x * 256 + threadIdx.x;
  if (e < NE) {
    int p = atomicAdd(&cursor[dst[e]], 1);
    ssrc[p] = src[e];
  }
}

// ---------------- weight convert: fp32 [K][Nout] (+optional second) -> bf16 B^T [Nout][Kpad]
__global__ void k_wconv(const float* __restrict__ W1, int K1,
                        const float* __restrict__ W2, int K2,
                        int Kpad, int Nout, u16* __restrict__ Bt) {
  int idx = blockIdx.x * 256 + threadIdx.x;
  if (idx >= Nout * Kpad) return;
  int n = idx / Kpad, k = idx % Kpad;
  float v = 0.0f;
  if (k < K1)            v = W1[(size_t)k * Nout + n];
  else if (k < K1 + K2)  v = W2[(size_t)(k - K1) * Nout + n];
  Bt[idx] = f2b(v);
}

// ---------------- A0 = [bf16(feature) | bf16(mean-agg(feature)) | zeros], [MPAD][64]
__global__ void k_build_A0(const float* __restrict__ feat, const int* __restrict__ rowptr,
                           const int* __restrict__ ssrc, const float* __restrict__ invdeg,
                           u16* __restrict__ A0) {
  const int r = blockIdx.x, t = threadIdx.x; // 64 threads
  u16* row = A0 + (size_t)r * 64;
  if (r >= NN) { row[t] = 0; return; }
  if (t < IN) {
    row[t] = f2b(feat[(size_t)r * IN + t]);
    float s = 0.0f;
    const int e0 = rowptr[r], e1 = rowptr[r + 1];
    for (int e = e0; e < e1; ++e) s += feat[(size_t)ssrc[e] * IN + t];
    row[IN + t] = f2b(s * invdeg[r]);
  } else if (t >= 2 * IN) {
    row[t] = 0;
  }
}

// ---------------- agg over 512 bf16 cols of A1 (h0 half) -> A1 cols 512..1023
__global__ void k_agg512(u16* __restrict__ A1, const int* __restrict__ rowptr,
                         const int* __restrict__ ssrc, const float* __restrict__ invdeg) {
  const int r = blockIdx.x, t = threadIdx.x; // 128 threads, 4 cols each
  float a0 = 0, a1 = 0, a2 = 0, a3 = 0;
  const int e0 = rowptr[r], e1 = rowptr[r + 1];
  for (int e = e0; e < e1; ++e) {
    const u16x4 v = *(const u16x4*)(A1 + (size_t)ssrc[e] * 1024 + t * 4);
    a0 += b2f(v.x); a1 += b2f(v.y); a2 += b2f(v.z); a3 += b2f(v.w);
  }
  const float inv = invdeg[r];
  u16x4 o; o.x = f2b(a0 * inv); o.y = f2b(a1 * inv); o.z = f2b(a2 * inv); o.w = f2b(a3 * inv);
  *(u16x4*)(A1 + (size_t)r * 1024 + 512 + t * 4) = o;
}

// ---------------- agg over 256 bf16 cols of T2 -> AGG2 fp32 [NN][256]
__global__ void k_agg256(const u16* __restrict__ T2, const int* __restrict__ rowptr,
                         const int* __restrict__ ssrc, const float* __restrict__ invdeg,
                         float* __restrict__ AGG2) {
  const int r = blockIdx.x, t = threadIdx.x; // 64 threads, 4 cols each
  float a0 = 0, a1 = 0, a2 = 0, a3 = 0;
  const int e0 = rowptr[r], e1 = rowptr[r + 1];
  for (int e = e0; e < e1; ++e) {
    const u16x4 v = *(const u16x4*)(T2 + (size_t)ssrc[e] * 256 + t * 4);
    a0 += b2f(v.x); a1 += b2f(v.y); a2 += b2f(v.z); a3 += b2f(v.w);
  }
  const float inv = invdeg[r];
  f32x4 o = {a0 * inv, a1 * inv, a2 * inv, a3 * inv};
  *(f32x4*)(AGG2 + (size_t)r * 256 + t * 4) = o;
}

// ---------------- MFMA GEMM: D = A[MPAD][lda](bf16) x Bt[Nout][K](bf16)^T tiles 128x128
// flags: 1 = relu (bf16 out), 2 = fp32 out to d_out with row<NN guard (+addp)
__global__ __launch_bounds__(256) void k_gemm(
    const u16* __restrict__ A, int lda,
    const u16* __restrict__ Bt, int K,
    void* __restrict__ Out, int ldo,
    const float* __restrict__ bias,
    const float* __restrict__ addp,
    int flags) {
  __shared__ u16 As[128 * 64];
  __shared__ u16 Bs[128 * 64];
  const int tid = threadIdx.x;
  const int wid = tid >> 6, lane = tid & 63;
  const int l16 = lane & 15, lhi = lane >> 4;
  const int wr = wid >> 1, wc = wid & 1;
  const int row0 = blockIdx.x * 128, col0 = blockIdx.y * 128;

  // staging decomposition: each thread owns one 16B slot; swizzle the GLOBAL
  // source slot so a swizzled ds_read_b128 sees linear data (rule 21)
  const int tr    = tid >> 3;              // row within 32-row issue
  const int slot  = tid & 7;               // 16B slot within 128B row
  const int sslot = slot ^ (tr & 7);       // inverse-swizzled source slot

  f32x4 acc[4][4] = {};

  for (int kt = 0; kt < K; kt += 64) {
#pragma unroll
    for (int i = 0; i < 4; ++i) {
      const int r = i * 32 + tr;
      gload_lds16(A  + (size_t)(row0 + r) * lda + kt + sslot * 8, &As[i * 2048 + wid * 512]);
      gload_lds16(Bt + (size_t)(col0 + r) * K   + kt + sslot * 8, &Bs[i * 2048 + wid * 512]);
    }
    __syncthreads();
#pragma unroll
    for (int ks = 0; ks < 2; ++ks) {
      bf16x8 af[4], bfr[4];
#pragma unroll
      for (int i = 0; i < 4; ++i) {
        const int r = wr * 64 + i * 16 + l16;
        const int s = (ks * 4 + lhi) ^ (r & 7);
        af[i] = *(const bf16x8*)&As[r * 64 + s * 8];
      }
#pragma unroll
      for (int n = 0; n < 4; ++n) {
        const int c = wc * 64 + n * 16 + l16;
        const int s = (ks * 4 + lhi) ^ (c & 7);
        bfr[n] = *(const bf16x8*)&Bs[c * 64 + s * 8];
      }
#pragma unroll
      for (int i = 0; i < 4; ++i)
#pragma unroll
        for (int n = 0; n < 4; ++n)
          acc[i][n] = __builtin_amdgcn_mfma_f32_16x16x32_bf16(af[i], bfr[n], acc[i][n], 0, 0, 0);
    }
    __syncthreads();
  }

  const bool relu = flags & 1;
  const bool f32o = flags & 2;
#pragma unroll
  for (int i = 0; i < 4; ++i) {
#pragma unroll
    for (int n = 0; n < 4; ++n) {
      const int C = col0 + wc * 64 + n * 16 + l16;
      const float bv = bias ? bias[C] : 0.0f;
#pragma unroll
      for (int q = 0; q < 4; ++q) {
        const int R = row0 + wr * 64 + i * 16 + lhi * 4 + q;
        float v = acc[i][n][q] + bv;
        if (f32o) {
          if (R < NN) {
            if (addp) v += addp[(size_t)R * ldo + C];
            ((float*)Out)[(size_t)R * ldo + C] = v;
          }
        } else {
          if (relu) v = fmaxf(v, 0.0f);
          ((u16*)Out)[(size_t)R * ldo + C] = f2b(v);
        }
      }
    }
  }
}

// ---------------- pooling ----------------
// graph_ids are sorted: gstart[g] = lower_bound(gid, g). One wave, no atomics.
__global__ void k_gbounds(const int* __restrict__ gid, int* __restrict__ gstart) {
  const int g = threadIdx.x;
  if (g > NG) return;
  int lo = 0, hi = NN;
  while (lo < hi) {
    const int mid = (lo + hi) >> 1;
    if (gid[mid] < g) lo = mid + 1; else hi = mid;
  }
  gstart[g] = lo;
}
__global__ void k_pool(const float* __restrict__ h, const int* __restrict__ gstart,
                       float* __restrict__ hg) {
  const int g = blockIdx.x >> 3, s = blockIdx.x & 7;
  const int t = threadIdx.x; // 256 = output col
  const int n0 = gstart[g], n1 = gstart[g + 1];
  const int len = n1 - n0, chunk = (len + 7) / 8;
  const int a = n0 + s * chunk;
  const int b = min(a + chunk, n1);
  float acc = 0.0f;
  for (int i = a; i < b; ++i) acc += h[(size_t)i * 256 + t];
  if (b > a) atomicAdd(&hg[g * 256 + t], acc);
}
__global__ void k_pooldiv(float* __restrict__ hg, const int* __restrict__ gstart) {
  const int g = blockIdx.x, t = threadIdx.x;
  const float c = (float)(gstart[g + 1] - gstart[g]);
  hg[g * 256 + t] /= fmaxf(c, 1.0f);
}

// ---------------- workspace layout (bytes) ----------------
constexpr size_t OFF_A0    = 0;                                   // [MPAD][64] bf16
constexpr size_t OFF_A1    = OFF_A0   + (size_t)MPAD * 64  * 2;   // [MPAD][1024] bf16 (h0|agg1)
constexpr size_t OFF_H1    = OFF_A1   + (size_t)MPAD * 1024 * 2;  // [MPAD][512] bf16
constexpr size_t OFF_T2    = OFF_H1   + (size_t)MPAD * 512 * 2;   // [MPAD][256] bf16
constexpr size_t OFF_AGG2  = OFF_T2   + (size_t)MPAD * 256 * 2;   // [NN][256] fp32
constexpr size_t OFF_BT0   = OFF_AGG2 + (size_t)NN * 256 * 4;     // [512][64] bf16
constexpr size_t OFF_BT1   = OFF_BT0  + (size_t)512 * 64 * 2;     // [512][1024] bf16
constexpr size_t OFF_BTS2  = OFF_BT1  + (size_t)512 * 1024 * 2;   // [256][512] bf16
constexpr size_t OFF_BTN2  = OFF_BTS2 + (size_t)256 * 512 * 2;    // [256][512] bf16
constexpr size_t OFF_DEG   = OFF_BTN2 + (size_t)256 * 512 * 2;    // [NN] int
constexpr size_t OFF_RP    = OFF_DEG  + (size_t)NN * 4;           // [NN+1] int
constexpr size_t OFF_CUR   = OFF_RP   + (size_t)(NN + 2) * 4;     // [NN] int
constexpr size_t OFF_SSRC  = OFF_CUR  + (size_t)NN * 4;           // [NE] int
constexpr size_t OFF_INVD  = OFF_SSRC + (size_t)NE * 4;           // [NN] float
constexpr size_t OFF_GST   = OFF_INVD + (size_t)NN * 4;           // [NG+1] int

extern "C" void kernel_launch(void* const* d_in, const int* in_sizes, int n_in,
                              void* d_out, int out_size, void* d_ws, size_t ws_size,
                              hipStream_t stream) {
  const float* feature = (const float*)d_in[0];
  const int*   esrc    = (const int*)d_in[1];
  const int*   edst    = (const int*)d_in[2];
  const int*   gid     = (const int*)d_in[3];
  const float* Ws0 = (const float*)d_in[4],  *Wn0 = (const float*)d_in[5],  *b0 = (const float*)d_in[6];
  const float* Ws1 = (const float*)d_in[7],  *Wn1 = (const float*)d_in[8],  *b1 = (const float*)d_in[9];
  const float* Ws2 = (const float*)d_in[10], *Wn2 = (const float*)d_in[11], *b2 = (const float*)d_in[12];

  char* ws = (char*)d_ws;
  u16*   A0    = (u16*)  (ws + OFF_A0);
  u16*   A1    = (u16*)  (ws + OFF_A1);
  u16*   H1    = (u16*)  (ws + OFF_H1);
  u16*   T2    = (u16*)  (ws + OFF_T2);
  float* AGG2  = (float*)(ws + OFF_AGG2);
  u16*   Bt0   = (u16*)  (ws + OFF_BT0);
  u16*   Bt1   = (u16*)  (ws + OFF_BT1);
  u16*   BtS2  = (u16*)  (ws + OFF_BTS2);
  u16*   BtN2  = (u16*)  (ws + OFF_BTN2);
  int*   deg   = (int*)  (ws + OFF_DEG);
  int*   rp    = (int*)  (ws + OFF_RP);
  int*   cur   = (int*)  (ws + OFF_CUR);
  int*   ssrc  = (int*)  (ws + OFF_SSRC);
  float* invd  = (float*)(ws + OFF_INVD);
  int*   gst   = (int*)  (ws + OFF_GST);

  float* out_h  = (float*)d_out;
  float* out_hg = out_h + (size_t)NN * OUT;

  hipMemsetAsync(deg,  0, (size_t)NN * 4, stream);
  hipMemsetAsync(out_hg, 0, (size_t)NG * OUT * 4, stream);

  // CSR by dst
  k_deg    <<<(NE + 255) / 256, 256, 0, stream>>>(edst, deg);
  k_scan   <<<1, 1024, 0, stream>>>(deg, rp, cur, invd);
  k_scatter<<<(NE + 255) / 256, 256, 0, stream>>>(esrc, edst, cur, ssrc);

  // weights -> bf16 B^T
  k_wconv<<<(512 * 64   + 255) / 256, 256, 0, stream>>>(Ws0, IN,  Wn0, IN,  64,   512, Bt0);
  k_wconv<<<(512 * 1024 + 255) / 256, 256, 0, stream>>>(Ws1, HID, Wn1, HID, 1024, 512, Bt1);
  k_wconv<<<(256 * 512  + 255) / 256, 256, 0, stream>>>(Ws2, HID, nullptr, 0, 512, 256, BtS2);
  k_wconv<<<(256 * 512  + 255) / 256, 256, 0, stream>>>(Wn2, HID, nullptr, 0, 512, 256, BtN2);

  // layer 0: A0 = [f | agg(f)], h0 = relu(A0 @ [Ws0;Wn0] + b0) -> A1[:, :512]
  k_build_A0<<<MPAD, 64, 0, stream>>>(feature, rp, ssrc, invd, A0);
  k_gemm<<<dim3(MT, 4), 256, 0, stream>>>(A0, 64, Bt0, 64, A1, 1024, b0, nullptr, 1);

  // layer 1: agg1 -> A1[:, 512:], h1 = relu(A1 @ [Ws1;Wn1] + b1)
  k_agg512<<<NN, 128, 0, stream>>>(A1, rp, ssrc, invd);
  k_gemm<<<dim3(MT, 4), 256, 0, stream>>>(A1, 1024, Bt1, 1024, H1, 512, b1, nullptr, 1);

  // layer 2: t2 = h1 @ Wn2; agg2 = mean(t2); out = h1 @ Ws2 + agg2 + b2
  k_gemm<<<dim3(MT, 2), 256, 0, stream>>>(H1, 512, BtN2, 512, T2, 256, nullptr, nullptr, 0);
  k_agg256<<<NN, 64, 0, stream>>>(T2, rp, ssrc, invd, AGG2);
  k_gemm<<<dim3(MT, 2), 256, 0, stream>>>(H1, 512, BtS2, 512, out_h, 256, b2, AGG2, 2);

  // avg pooling per graph (graph_ids sorted -> binary-search boundaries)
  k_gbounds<<<1, 64, 0, stream>>>(gid, gst);
  k_pool   <<<NG * 8, 256, 0, stream>>>(out_h, gst, out_hg);
  k_pooldiv<<<NG, 256, 0, stream>>>(out_hg, gst);
}

// Round 5
// 331.636 us; speedup vs baseline: 1.3997x; 1.0413x over previous
//
#include <hip/hip_runtime.h>

// ---------------- problem constants ----------------
constexpr int NN   = 20000;   // nodes
constexpr int NE   = 160000;  // edges
constexpr int NG   = 32;      // graphs
constexpr int IN   = 27;
constexpr int HID  = 512;
constexpr int OUT  = 256;
constexpr int MPAD = 20096;   // 157 * 128
constexpr int MT   = MPAD / 128; // 157 m-tiles

typedef unsigned short u16;
typedef __bf16 bf16x8 __attribute__((ext_vector_type(8)));
typedef float  f32x4  __attribute__((ext_vector_type(4)));
typedef u16    u16x4  __attribute__((ext_vector_type(4)));

__device__ __forceinline__ u16 f2b(float x) {
  __bf16 h = (__bf16)x;                 // RNE convert
  return __builtin_bit_cast(u16, h);
}
__device__ __forceinline__ float b2f(u16 u) {
  __bf16 h = __builtin_bit_cast(__bf16, u);
  return (float)h;
}

#define GLOBAL_AS __attribute__((address_space(1)))
#define LDS_AS    __attribute__((address_space(3)))
__device__ __forceinline__ void gload_lds16(const void* g, void* l) {
  __builtin_amdgcn_global_load_lds((const GLOBAL_AS void*)g, (LDS_AS void*)l, 16, 0, 0);
}

// ---------------- CSR build ----------------
__global__ void k_deg(const int* __restrict__ dst, int* __restrict__ deg) {
  int e = blockIdx.x * 256 + threadIdx.x;
  if (e < NE) atomicAdd(&deg[dst[e]], 1);
}

// single-block scan, thread-serial chunks + wave shuffle scan (2 barriers total)
__global__ void k_scan(const int* __restrict__ deg, int* __restrict__ rowptr,
                       int* __restrict__ cursor, float* __restrict__ invdeg) {
  constexpr int CH = 20;                 // 1024 * 20 = 20480 >= NN
  __shared__ int wsum[16];
  const int tid = threadIdx.x;
  const int i0 = tid * CH;
  int loc[CH];
  int sum = 0;
#pragma unroll
  for (int j = 0; j < CH; ++j) {
    const int i = i0 + j;
    loc[j] = sum;                        // exclusive prefix within chunk
    sum += (i < NN) ? deg[i] : 0;
  }
  const int lane = tid & 63, wv = tid >> 6;
  int incl = sum;                        // wave-inclusive scan of chunk sums
#pragma unroll
  for (int off = 1; off < 64; off <<= 1) {
    int n = __shfl_up(incl, off);
    if (lane >= off) incl += n;
  }
  if (lane == 63) wsum[wv] = incl;
  __syncthreads();
  if (tid == 0) {
    int s = 0;
#pragma unroll
    for (int w = 0; w < 16; ++w) { int v = wsum[w]; wsum[w] = s + v; s += v; }
  }
  __syncthreads();
  const int wbase = (wv == 0) ? 0 : wsum[wv - 1];
  const int tbase = wbase + incl - sum;  // exclusive prefix of this chunk
#pragma unroll
  for (int j = 0; j < CH; ++j) {
    const int i = i0 + j;
    if (i < NN) {
      const int excl = tbase + loc[j];
      const int d = ((j + 1 < CH) ? loc[j + 1] : sum) - loc[j];
      rowptr[i] = excl;
      cursor[i] = excl;
      invdeg[i] = 1.0f / fmaxf((float)d, 1.0f);
    }
  }
  if (tid == 0) rowptr[NN] = wsum[15];
}

__global__ void k_scatter(const int* __restrict__ src, const int* __restrict__ dst,
                          int* __restrict__ cursor, int* __restrict__ ssrc) {
  int e = blockIdx.x * 256 + threadIdx.x;
  if (e < NE) {
    int p = atomicAdd(&cursor[dst[e]], 1);
    ssrc[p] = src[e];
  }
}

// ---------------- fused weight convert: all fp32 W -> bf16 B^T buffers in one dispatch
constexpr int WC0 = 512 * 64;     // Bt0 elems
constexpr int WC1 = 512 * 1024;   // Bt1 elems
constexpr int WC2 = 256 * 512;    // BtS2 / BtN2 elems
constexpr int WCT = WC0 + WC1 + 2 * WC2;   // 819200
__global__ void k_wconv_all(const float* __restrict__ Ws0, const float* __restrict__ Wn0,
                            const float* __restrict__ Ws1, const float* __restrict__ Wn1,
                            const float* __restrict__ Ws2, const float* __restrict__ Wn2,
                            u16* __restrict__ Bt0, u16* __restrict__ Bt1,
                            u16* __restrict__ BtS2, u16* __restrict__ BtN2) {
  int idx = blockIdx.x * 256 + threadIdx.x;
  if (idx < WC0) {
    const int n = idx / 64, k = idx % 64;
    float v = 0.0f;
    if (k < IN)           v = Ws0[(size_t)k * 512 + n];
    else if (k < 2 * IN)  v = Wn0[(size_t)(k - IN) * 512 + n];
    Bt0[idx] = f2b(v);
    return;
  }
  idx -= WC0;
  if (idx < WC1) {
    const int n = idx / 1024, k = idx % 1024;
    const float v = (k < 512) ? Ws1[(size_t)k * 512 + n] : Wn1[(size_t)(k - 512) * 512 + n];
    Bt1[idx] = f2b(v);
    return;
  }
  idx -= WC1;
  if (idx < WC2) {
    const int n = idx / 512, k = idx % 512;
    BtS2[idx] = f2b(Ws2[(size_t)k * 256 + n]);
    return;
  }
  idx -= WC2;
  if (idx < WC2) {
    const int n = idx / 512, k = idx % 512;
    BtN2[idx] = f2b(Wn2[(size_t)k * 256 + n]);
  }
}

// ---------------- A0 = [bf16(feature) | bf16(mean-agg(feature)) | zeros], [MPAD][64]
__global__ void k_build_A0(const float* __restrict__ feat, const int* __restrict__ rowptr,
                           const int* __restrict__ ssrc, const float* __restrict__ invdeg,
                           u16* __restrict__ A0) {
  const int r = blockIdx.x, t = threadIdx.x; // 64 threads
  u16* row = A0 + (size_t)r * 64;
  if (r >= NN) { row[t] = 0; return; }
  if (t < IN) {
    row[t] = f2b(feat[(size_t)r * IN + t]);
    float s = 0.0f;
    const int e0 = rowptr[r], e1 = rowptr[r + 1];
    for (int e = e0; e < e1; ++e) s += feat[(size_t)ssrc[e] * IN + t];
    row[IN + t] = f2b(s * invdeg[r]);
  } else if (t >= 2 * IN) {
    row[t] = 0;
  }
}

// ---------------- agg over 512 bf16 cols of A1 (h0 half) -> A1 cols 512..1023
__global__ void k_agg512(u16* __restrict__ A1, const int* __restrict__ rowptr,
                         const int* __restrict__ ssrc, const float* __restrict__ invdeg) {
  const int r = blockIdx.x, t = threadIdx.x; // 128 threads, 4 cols each
  float a0 = 0, a1 = 0, a2 = 0, a3 = 0;
  const int e0 = rowptr[r], e1 = rowptr[r + 1];
  for (int e = e0; e < e1; ++e) {
    const u16x4 v = *(const u16x4*)(A1 + (size_t)ssrc[e] * 1024 + t * 4);
    a0 += b2f(v.x); a1 += b2f(v.y); a2 += b2f(v.z); a3 += b2f(v.w);
  }
  const float inv = invdeg[r];
  u16x4 o; o.x = f2b(a0 * inv); o.y = f2b(a1 * inv); o.z = f2b(a2 * inv); o.w = f2b(a3 * inv);
  *(u16x4*)(A1 + (size_t)r * 1024 + 512 + t * 4) = o;
}

// ---------------- agg over 256 bf16 cols of T2 -> AGG2 fp32 [NN][256]
__global__ void k_agg256(const u16* __restrict__ T2, const int* __restrict__ rowptr,
                         const int* __restrict__ ssrc, const float* __restrict__ invdeg,
                         float* __restrict__ AGG2) {
  const int r = blockIdx.x, t = threadIdx.x; // 64 threads, 4 cols each
  float a0 = 0, a1 = 0, a2 = 0, a3 = 0;
  const int e0 = rowptr[r], e1 = rowptr[r + 1];
  for (int e = e0; e < e1; ++e) {
    const u16x4 v = *(const u16x4*)(T2 + (size_t)ssrc[e] * 256 + t * 4);
    a0 += b2f(v.x); a1 += b2f(v.y); a2 += b2f(v.z); a3 += b2f(v.w);
  }
  const float inv = invdeg[r];
  f32x4 o = {a0 * inv, a1 * inv, a2 * inv, a3 * inv};
  *(f32x4*)(AGG2 + (size_t)r * 256 + t * 4) = o;
}

// ---------------- MFMA GEMM: D = A[MPAD][lda](bf16) x Bt[Nout][K](bf16)^T tiles 128x128
// flags: 1 = relu (bf16 out), 2 = fp32 out to d_out with row<NN guard (+addp)
__global__ __launch_bounds__(256) void k_gemm(
    const u16* __restrict__ A, int lda,
    const u16* __restrict__ Bt, int K,
    void* __restrict__ Out, int ldo,
    const float* __restrict__ bias,
    const float* __restrict__ addp,
    int flags) {
  __shared__ u16 As[128 * 64];
  __shared__ u16 Bs[128 * 64];
  const int tid = threadIdx.x;
  const int wid = tid >> 6, lane = tid & 63;
  const int l16 = lane & 15, lhi = lane >> 4;
  const int wr = wid >> 1, wc = wid & 1;
  const int row0 = blockIdx.x * 128, col0 = blockIdx.y * 128;

  // staging decomposition: each thread owns one 16B slot; swizzle the GLOBAL
  // source slot so a swizzled ds_read_b128 sees linear data (rule 21)
  const int tr    = tid >> 3;              // row within 32-row issue
  const int slot  = tid & 7;               // 16B slot within 128B row
  const int sslot = slot ^ (tr & 7);       // inverse-swizzled source slot

  f32x4 acc[4][4] = {};

  for (int kt = 0; kt < K; kt += 64) {
#pragma unroll
    for (int i = 0; i < 4; ++i) {
      const int r = i * 32 + tr;
      gload_lds16(A  + (size_t)(row0 + r) * lda + kt + sslot * 8, &As[i * 2048 + wid * 512]);
      gload_lds16(Bt + (size_t)(col0 + r) * K   + kt + sslot * 8, &Bs[i * 2048 + wid * 512]);
    }
    __syncthreads();
#pragma unroll
    for (int ks = 0; ks < 2; ++ks) {
      bf16x8 af[4], bfr[4];
#pragma unroll
      for (int i = 0; i < 4; ++i) {
        const int r = wr * 64 + i * 16 + l16;
        const int s = (ks * 4 + lhi) ^ (r & 7);
        af[i] = *(const bf16x8*)&As[r * 64 + s * 8];
      }
#pragma unroll
      for (int n = 0; n < 4; ++n) {
        const int c = wc * 64 + n * 16 + l16;
        const int s = (ks * 4 + lhi) ^ (c & 7);
        bfr[n] = *(const bf16x8*)&Bs[c * 64 + s * 8];
      }
#pragma unroll
      for (int i = 0; i < 4; ++i)
#pragma unroll
        for (int n = 0; n < 4; ++n)
          acc[i][n] = __builtin_amdgcn_mfma_f32_16x16x32_bf16(af[i], bfr[n], acc[i][n], 0, 0, 0);
    }
    __syncthreads();
  }

  const bool relu = flags & 1;
  const bool f32o = flags & 2;
#pragma unroll
  for (int i = 0; i < 4; ++i) {
#pragma unroll
    for (int n = 0; n < 4; ++n) {
      const int C = col0 + wc * 64 + n * 16 + l16;
      const float bv = bias ? bias[C] : 0.0f;
#pragma unroll
      for (int q = 0; q < 4; ++q) {
        const int R = row0 + wr * 64 + i * 16 + lhi * 4 + q;
        float v = acc[i][n][q] + bv;
        if (f32o) {
          if (R < NN) {
            if (addp) v += addp[(size_t)R * ldo + C];
            ((float*)Out)[(size_t)R * ldo + C] = v;
          }
        } else {
          if (relu) v = fmaxf(v, 0.0f);
          ((u16*)Out)[(size_t)R * ldo + C] = f2b(v);
        }
      }
    }
  }
}

// ---------------- pooling (graph_ids sorted; binary search in-kernel) ----------------
__device__ __forceinline__ int lower_bound_g(const int* __restrict__ gid, int g) {
  int lo = 0, hi = NN;
  while (lo < hi) {
    const int mid = (lo + hi) >> 1;
    if (gid[mid] < g) lo = mid + 1; else hi = mid;
  }
  return lo;
}
__global__ void k_pool(const float* __restrict__ h, const int* __restrict__ gid,
                       float* __restrict__ hg) {
  __shared__ int s_n0, s_n1;
  const int g = blockIdx.x >> 3, s = blockIdx.x & 7;
  const int t = threadIdx.x; // 256 = output col
  if (t == 0) { s_n0 = lower_bound_g(gid, g); s_n1 = lower_bound_g(gid, g + 1); }
  __syncthreads();
  const int n0 = s_n0, n1 = s_n1;
  const int len = n1 - n0, chunk = (len + 7) / 8;
  const int a = n0 + s * chunk;
  const int b = min(a + chunk, n1);
  float acc = 0.0f;
  for (int i = a; i < b; ++i) acc += h[(size_t)i * 256 + t];
  if (b > a) atomicAdd(&hg[g * 256 + t], acc);
}
__global__ void k_pooldiv(float* __restrict__ hg, const int* __restrict__ gid) {
  __shared__ int s_c;
  const int g = blockIdx.x, t = threadIdx.x;
  if (t == 0) s_c = lower_bound_g(gid, g + 1) - lower_bound_g(gid, g);
  __syncthreads();
  hg[g * 256 + t] /= fmaxf((float)s_c, 1.0f);
}

// ---------------- workspace layout (bytes) ----------------
constexpr size_t OFF_A0    = 0;                                   // [MPAD][64] bf16
constexpr size_t OFF_A1    = OFF_A0   + (size_t)MPAD * 64  * 2;   // [MPAD][1024] bf16 (h0|agg1)
constexpr size_t OFF_H1    = OFF_A1   + (size_t)MPAD * 1024 * 2;  // [MPAD][512] bf16
constexpr size_t OFF_T2    = OFF_H1   + (size_t)MPAD * 512 * 2;   // [MPAD][256] bf16
constexpr size_t OFF_AGG2  = OFF_T2   + (size_t)MPAD * 256 * 2;   // [NN][256] fp32
constexpr size_t OFF_BT0   = OFF_AGG2 + (size_t)NN * 256 * 4;     // [512][64] bf16
constexpr size_t OFF_BT1   = OFF_BT0  + (size_t)512 * 64 * 2;     // [512][1024] bf16
constexpr size_t OFF_BTS2  = OFF_BT1  + (size_t)512 * 1024 * 2;   // [256][512] bf16
constexpr size_t OFF_BTN2  = OFF_BTS2 + (size_t)256 * 512 * 2;    // [256][512] bf16
constexpr size_t OFF_DEG   = OFF_BTN2 + (size_t)256 * 512 * 2;    // [NN] int
constexpr size_t OFF_RP    = OFF_DEG  + (size_t)NN * 4;           // [NN+1] int
constexpr size_t OFF_CUR   = OFF_RP   + (size_t)(NN + 2) * 4;     // [NN] int
constexpr size_t OFF_SSRC  = OFF_CUR  + (size_t)NN * 4;           // [NE] int
constexpr size_t OFF_INVD  = OFF_SSRC + (size_t)NE * 4;           // [NN] float

extern "C" void kernel_launch(void* const* d_in, const int* in_sizes, int n_in,
                              void* d_out, int out_size, void* d_ws, size_t ws_size,
                              hipStream_t stream) {
  const float* feature = (const float*)d_in[0];
  const int*   esrc    = (const int*)d_in[1];
  const int*   edst    = (const int*)d_in[2];
  const int*   gid     = (const int*)d_in[3];
  const float* Ws0 = (const float*)d_in[4],  *Wn0 = (const float*)d_in[5],  *b0 = (const float*)d_in[6];
  const float* Ws1 = (const float*)d_in[7],  *Wn1 = (const float*)d_in[8],  *b1 = (const float*)d_in[9];
  const float* Ws2 = (const float*)d_in[10], *Wn2 = (const float*)d_in[11], *b2 = (const float*)d_in[12];

  char* ws = (char*)d_ws;
  u16*   A0    = (u16*)  (ws + OFF_A0);
  u16*   A1    = (u16*)  (ws + OFF_A1);
  u16*   H1    = (u16*)  (ws + OFF_H1);
  u16*   T2    = (u16*)  (ws + OFF_T2);
  float* AGG2  = (float*)(ws + OFF_AGG2);
  u16*   Bt0   = (u16*)  (ws + OFF_BT0);
  u16*   Bt1   = (u16*)  (ws + OFF_BT1);
  u16*   BtS2  = (u16*)  (ws + OFF_BTS2);
  u16*   BtN2  = (u16*)  (ws + OFF_BTN2);
  int*   deg   = (int*)  (ws + OFF_DEG);
  int*   rp    = (int*)  (ws + OFF_RP);
  int*   cur   = (int*)  (ws + OFF_CUR);
  int*   ssrc  = (int*)  (ws + OFF_SSRC);
  float* invd  = (float*)(ws + OFF_INVD);

  float* out_h  = (float*)d_out;
  float* out_hg = out_h + (size_t)NN * OUT;

  hipMemsetAsync(deg,  0, (size_t)NN * 4, stream);
  hipMemsetAsync(out_hg, 0, (size_t)NG * OUT * 4, stream);

  // CSR by dst
  k_deg    <<<(NE + 255) / 256, 256, 0, stream>>>(edst, deg);
  k_scan   <<<1, 1024, 0, stream>>>(deg, rp, cur, invd);
  k_scatter<<<(NE + 255) / 256, 256, 0, stream>>>(esrc, edst, cur, ssrc);

  // weights -> bf16 B^T (single fused dispatch)
  k_wconv_all<<<(WCT + 255) / 256, 256, 0, stream>>>(Ws0, Wn0, Ws1, Wn1, Ws2, Wn2,
                                                     Bt0, Bt1, BtS2, BtN2);

  // layer 0: A0 = [f | agg(f)], h0 = relu(A0 @ [Ws0;Wn0] + b0) -> A1[:, :512]
  k_build_A0<<<MPAD, 64, 0, stream>>>(feature, rp, ssrc, invd, A0);
  k_gemm<<<dim3(MT, 4), 256, 0, stream>>>(A0, 64, Bt0, 64, A1, 1024, b0, nullptr, 1);

  // layer 1: agg1 -> A1[:, 512:], h1 = relu(A1 @ [Ws1;Wn1] + b1)
  k_agg512<<<NN, 128, 0, stream>>>(A1, rp, ssrc, invd);
  k_gemm<<<dim3(MT, 4), 256, 0, stream>>>(A1, 1024, Bt1, 1024, H1, 512, b1, nullptr, 1);

  // layer 2: t2 = h1 @ Wn2; agg2 = mean(t2); out = h1 @ Ws2 + agg2 + b2
  k_gemm<<<dim3(MT, 2), 256, 0, stream>>>(H1, 512, BtN2, 512, T2, 256, nullptr, nullptr, 0);
  k_agg256<<<NN, 64, 0, stream>>>(T2, rp, ssrc, invd, AGG2);
  k_gemm<<<dim3(MT, 2), 256, 0, stream>>>(H1, 512, BtS2, 512, out_h, 256, b2, AGG2, 2);

  // avg pooling per graph (graph_ids sorted -> in-kernel binary search)
  k_pool   <<<NG * 8, 256, 0, stream>>>(out_h, gid, out_hg);
  k_pooldiv<<<NG, 256, 0, stream>>>(out_hg, gid);
}

// Round 6
// 313.755 us; speedup vs baseline: 1.4795x; 1.0570x over previous
//
#include <hip/hip_runtime.h>

// ---------------- problem constants ----------------
constexpr int NN   = 20000;   // nodes
constexpr int NE   = 160000;  // edges
constexpr int NG   = 32;      // graphs
constexpr int IN   = 27;
constexpr int HID  = 512;
constexpr int OUT  = 256;
constexpr int MPAD = 20096;   // 157 * 128
constexpr int MT   = MPAD / 128; // 157 m-tiles

typedef unsigned short u16;
typedef __bf16 bf16x8 __attribute__((ext_vector_type(8)));
typedef float  f32x4  __attribute__((ext_vector_type(4)));
typedef u16    u16x4  __attribute__((ext_vector_type(4)));

__device__ __forceinline__ u16 f2b(float x) {
  __bf16 h = (__bf16)x;                 // RNE convert
  return __builtin_bit_cast(u16, h);
}
__device__ __forceinline__ float b2f(u16 u) {
  __bf16 h = __builtin_bit_cast(__bf16, u);
  return (float)h;
}

#define GLOBAL_AS __attribute__((address_space(1)))
#define LDS_AS    __attribute__((address_space(3)))
__device__ __forceinline__ void gload_lds16(const void* g, void* l) {
  __builtin_amdgcn_global_load_lds((const GLOBAL_AS void*)g, (LDS_AS void*)l, 16, 0, 0);
}

// ---------------- CSR build ----------------
__global__ void k_deg(const int* __restrict__ dst, int* __restrict__ deg) {
  int e = blockIdx.x * 256 + threadIdx.x;
  if (e < NE) atomicAdd(&deg[dst[e]], 1);
}

// single-block scan, thread-serial chunks + wave shuffle scan (2 barriers total)
__global__ void k_scan(const int* __restrict__ deg, int* __restrict__ rowptr,
                       int* __restrict__ cursor, float* __restrict__ invdeg) {
  constexpr int CH = 20;                 // 1024 * 20 = 20480 >= NN
  __shared__ int wsum[16];
  const int tid = threadIdx.x;
  const int i0 = tid * CH;
  int loc[CH];
  int sum = 0;
#pragma unroll
  for (int j = 0; j < CH; ++j) {
    const int i = i0 + j;
    loc[j] = sum;                        // exclusive prefix within chunk
    sum += (i < NN) ? deg[i] : 0;
  }
  const int lane = tid & 63, wv = tid >> 6;
  int incl = sum;                        // wave-inclusive scan of chunk sums
#pragma unroll
  for (int off = 1; off < 64; off <<= 1) {
    int n = __shfl_up(incl, off);
    if (lane >= off) incl += n;
  }
  if (lane == 63) wsum[wv] = incl;
  __syncthreads();
  if (tid == 0) {
    int s = 0;
#pragma unroll
    for (int w = 0; w < 16; ++w) { int v = wsum[w]; wsum[w] = s + v; s += v; }
  }
  __syncthreads();
  const int wbase = (wv == 0) ? 0 : wsum[wv - 1];
  const int tbase = wbase + incl - sum;  // exclusive prefix of this chunk
#pragma unroll
  for (int j = 0; j < CH; ++j) {
    const int i = i0 + j;
    if (i < NN) {
      const int excl = tbase + loc[j];
      const int d = ((j + 1 < CH) ? loc[j + 1] : sum) - loc[j];
      rowptr[i] = excl;
      cursor[i] = excl;
      invdeg[i] = 1.0f / fmaxf((float)d, 1.0f);
    }
  }
  if (tid == 0) rowptr[NN] = wsum[15];
}

__global__ void k_scatter(const int* __restrict__ src, const int* __restrict__ dst,
                          int* __restrict__ cursor, int* __restrict__ ssrc) {
  int e = blockIdx.x * 256 + threadIdx.x;
  if (e < NE) {
    int p = atomicAdd(&cursor[dst[e]], 1);
    ssrc[p] = src[e];
  }
}

// ---------------- fused weight convert: all fp32 W -> bf16 B^T buffers in one dispatch
constexpr int WC0 = 512 * 64;     // Bt0 elems   [512][64]   <- [Ws0;Wn0] padded
constexpr int WC1 = 512 * 1024;   // Bt1 elems   [512][1024] <- [Ws1;Wn1]
constexpr int WC2 = 256 * 1024;   // BtSN2 elems [256][1024] <- [Ws2;Wn2]
constexpr int WCT = WC0 + WC1 + WC2;
__global__ void k_wconv_all(const float* __restrict__ Ws0, const float* __restrict__ Wn0,
                            const float* __restrict__ Ws1, const float* __restrict__ Wn1,
                            const float* __restrict__ Ws2, const float* __restrict__ Wn2,
                            u16* __restrict__ Bt0, u16* __restrict__ Bt1,
                            u16* __restrict__ BtSN2) {
  int idx = blockIdx.x * 256 + threadIdx.x;
  if (idx < WC0) {
    const int n = idx / 64, k = idx % 64;
    float v = 0.0f;
    if (k < IN)           v = Ws0[(size_t)k * 512 + n];
    else if (k < 2 * IN)  v = Wn0[(size_t)(k - IN) * 512 + n];
    Bt0[idx] = f2b(v);
    return;
  }
  idx -= WC0;
  if (idx < WC1) {
    const int n = idx / 1024, k = idx % 1024;
    const float v = (k < 512) ? Ws1[(size_t)k * 512 + n] : Wn1[(size_t)(k - 512) * 512 + n];
    Bt1[idx] = f2b(v);
    return;
  }
  idx -= WC1;
  if (idx < WC2) {
    const int n = idx / 1024, k = idx % 1024;
    const float v = (k < 512) ? Ws2[(size_t)k * 256 + n] : Wn2[(size_t)(k - 512) * 256 + n];
    BtSN2[idx] = f2b(v);
  }
}

// ---------------- A0 = [bf16(feature) | bf16(mean-agg(feature)) | zeros], [MPAD][64]
__global__ void k_build_A0(const float* __restrict__ feat, const int* __restrict__ rowptr,
                           const int* __restrict__ ssrc, const float* __restrict__ invdeg,
                           u16* __restrict__ A0) {
  const int r = blockIdx.x, t = threadIdx.x; // 64 threads
  u16* row = A0 + (size_t)r * 64;
  if (r >= NN) { row[t] = 0; return; }
  if (t < IN) {
    row[t] = f2b(feat[(size_t)r * IN + t]);
    float s = 0.0f;
    const int e0 = rowptr[r], e1 = rowptr[r + 1];
    for (int e = e0; e < e1; ++e) s += feat[(size_t)ssrc[e] * IN + t];
    row[IN + t] = f2b(s * invdeg[r]);
  } else if (t >= 2 * IN) {
    row[t] = 0;
  }
}

// ---------------- agg over cols [0,512) of X[MPAD][1024] -> cols [512,1024)
__global__ void k_agg512(u16* __restrict__ X, const int* __restrict__ rowptr,
                         const int* __restrict__ ssrc, const float* __restrict__ invdeg) {
  const int r = blockIdx.x, t = threadIdx.x; // 128 threads, 4 cols each
  float a0 = 0, a1 = 0, a2 = 0, a3 = 0;
  const int e0 = rowptr[r], e1 = rowptr[r + 1];
  for (int e = e0; e < e1; ++e) {
    const u16x4 v = *(const u16x4*)(X + (size_t)ssrc[e] * 1024 + t * 4);
    a0 += b2f(v.x); a1 += b2f(v.y); a2 += b2f(v.z); a3 += b2f(v.w);
  }
  const float inv = invdeg[r];
  u16x4 o; o.x = f2b(a0 * inv); o.y = f2b(a1 * inv); o.z = f2b(a2 * inv); o.w = f2b(a3 * inv);
  *(u16x4*)(X + (size_t)r * 1024 + 512 + t * 4) = o;
}

// ---------------- MFMA GEMM: D = A[MPAD][lda](bf16) x Bt[Nout][K](bf16)^T tiles 128x128
// flags: 1 = relu (bf16 out), 2 = fp32 out to d_out with row<NN guard
__global__ __launch_bounds__(256) void k_gemm(
    const u16* __restrict__ A, int lda,
    const u16* __restrict__ Bt, int K,
    void* __restrict__ Out, int ldo,
    const float* __restrict__ bias,
    int flags) {
  __shared__ u16 As[128 * 64];
  __shared__ u16 Bs[128 * 64];
  const int tid = threadIdx.x;
  const int wid = tid >> 6, lane = tid & 63;
  const int l16 = lane & 15, lhi = lane >> 4;
  const int wr = wid >> 1, wc = wid & 1;
  const int row0 = blockIdx.x * 128, col0 = blockIdx.y * 128;

  // staging decomposition: each thread owns one 16B slot; swizzle the GLOBAL
  // source slot so a swizzled ds_read_b128 sees linear data (rule 21)
  const int tr    = tid >> 3;              // row within 32-row issue
  const int slot  = tid & 7;               // 16B slot within 128B row
  const int sslot = slot ^ (tr & 7);       // inverse-swizzled source slot

  f32x4 acc[4][4] = {};

  for (int kt = 0; kt < K; kt += 64) {
#pragma unroll
    for (int i = 0; i < 4; ++i) {
      const int r = i * 32 + tr;
      gload_lds16(A  + (size_t)(row0 + r) * lda + kt + sslot * 8, &As[i * 2048 + wid * 512]);
      gload_lds16(Bt + (size_t)(col0 + r) * K   + kt + sslot * 8, &Bs[i * 2048 + wid * 512]);
    }
    __syncthreads();
#pragma unroll
    for (int ks = 0; ks < 2; ++ks) {
      bf16x8 af[4], bfr[4];
#pragma unroll
      for (int i = 0; i < 4; ++i) {
        const int r = wr * 64 + i * 16 + l16;
        const int s = (ks * 4 + lhi) ^ (r & 7);
        af[i] = *(const bf16x8*)&As[r * 64 + s * 8];
      }
#pragma unroll
      for (int n = 0; n < 4; ++n) {
        const int c = wc * 64 + n * 16 + l16;
        const int s = (ks * 4 + lhi) ^ (c & 7);
        bfr[n] = *(const bf16x8*)&Bs[c * 64 + s * 8];
      }
#pragma unroll
      for (int i = 0; i < 4; ++i)
#pragma unroll
        for (int n = 0; n < 4; ++n)
          acc[i][n] = __builtin_amdgcn_mfma_f32_16x16x32_bf16(af[i], bfr[n], acc[i][n], 0, 0, 0);
    }
    __syncthreads();
  }

  const bool relu = flags & 1;
  const bool f32o = flags & 2;
#pragma unroll
  for (int i = 0; i < 4; ++i) {
#pragma unroll
    for (int n = 0; n < 4; ++n) {
      const int C = col0 + wc * 64 + n * 16 + l16;
      const float bv = bias ? bias[C] : 0.0f;
#pragma unroll
      for (int q = 0; q < 4; ++q) {
        const int R = row0 + wr * 64 + i * 16 + lhi * 4 + q;
        float v = acc[i][n][q] + bv;
        if (f32o) {
          if (R < NN) ((float*)Out)[(size_t)R * ldo + C] = v;
        } else {
          if (relu) v = fmaxf(v, 0.0f);
          ((u16*)Out)[(size_t)R * ldo + C] = f2b(v);
        }
      }
    }
  }
}

// ---------------- pooling (graph_ids sorted; binary search in-kernel) ----------------
__device__ __forceinline__ int lower_bound_g(const int* __restrict__ gid, int g) {
  int lo = 0, hi = NN;
  while (lo < hi) {
    const int mid = (lo + hi) >> 1;
    if (gid[mid] < g) lo = mid + 1; else hi = mid;
  }
  return lo;
}
// partial sums pre-scaled by 1/count -> no separate divide pass
__global__ void k_pool(const float* __restrict__ h, const int* __restrict__ gid,
                       float* __restrict__ hg) {
  __shared__ int s_n0, s_n1;
  const int g = blockIdx.x >> 3, s = blockIdx.x & 7;
  const int t = threadIdx.x; // 256 = output col
  if (t == 0) { s_n0 = lower_bound_g(gid, g); s_n1 = lower_bound_g(gid, g + 1); }
  __syncthreads();
  const int n0 = s_n0, n1 = s_n1;
  const int len = n1 - n0, chunk = (len + 7) / 8;
  const int a = n0 + s * chunk;
  const int b = min(a + chunk, n1);
  float acc = 0.0f;
  for (int i = a; i < b; ++i) acc += h[(size_t)i * 256 + t];
  if (b > a) {
    const float inv = 1.0f / fmaxf((float)len, 1.0f);
    atomicAdd(&hg[g * 256 + t], acc * inv);
  }
}

// ---------------- workspace layout (bytes) ----------------
constexpr size_t OFF_A0    = 0;                                   // [MPAD][64] bf16
constexpr size_t OFF_A1    = OFF_A0   + (size_t)MPAD * 64  * 2;   // [MPAD][1024] bf16 (h0|agg h0)
constexpr size_t OFF_A2    = OFF_A1   + (size_t)MPAD * 1024 * 2;  // [MPAD][1024] bf16 (h1|agg h1)
constexpr size_t OFF_BT0   = OFF_A2   + (size_t)MPAD * 1024 * 2;  // [512][64] bf16
constexpr size_t OFF_BT1   = OFF_BT0  + (size_t)512 * 64 * 2;     // [512][1024] bf16
constexpr size_t OFF_BTSN2 = OFF_BT1  + (size_t)512 * 1024 * 2;   // [256][1024] bf16
constexpr size_t OFF_DEG   = OFF_BTSN2+ (size_t)256 * 1024 * 2;   // [NN] int
constexpr size_t OFF_RP    = OFF_DEG  + (size_t)NN * 4;           // [NN+1] int
constexpr size_t OFF_CUR   = OFF_RP   + (size_t)(NN + 2) * 4;     // [NN] int
constexpr size_t OFF_SSRC  = OFF_CUR  + (size_t)NN * 4;           // [NE] int
constexpr size_t OFF_INVD  = OFF_SSRC + (size_t)NE * 4;           // [NN] float

extern "C" void kernel_launch(void* const* d_in, const int* in_sizes, int n_in,
                              void* d_out, int out_size, void* d_ws, size_t ws_size,
                              hipStream_t stream) {
  const float* feature = (const float*)d_in[0];
  const int*   esrc    = (const int*)d_in[1];
  const int*   edst    = (const int*)d_in[2];
  const int*   gid     = (const int*)d_in[3];
  const float* Ws0 = (const float*)d_in[4],  *Wn0 = (const float*)d_in[5],  *b0 = (const float*)d_in[6];
  const float* Ws1 = (const float*)d_in[7],  *Wn1 = (const float*)d_in[8],  *b1 = (const float*)d_in[9];
  const float* Ws2 = (const float*)d_in[10], *Wn2 = (const float*)d_in[11], *b2 = (const float*)d_in[12];

  char* ws = (char*)d_ws;
  u16*   A0    = (u16*)  (ws + OFF_A0);
  u16*   A1    = (u16*)  (ws + OFF_A1);
  u16*   A2    = (u16*)  (ws + OFF_A2);
  u16*   Bt0   = (u16*)  (ws + OFF_BT0);
  u16*   Bt1   = (u16*)  (ws + OFF_BT1);
  u16*   BtSN2 = (u16*)  (ws + OFF_BTSN2);
  int*   deg   = (int*)  (ws + OFF_DEG);
  int*   rp    = (int*)  (ws + OFF_RP);
  int*   cur   = (int*)  (ws + OFF_CUR);
  int*   ssrc  = (int*)  (ws + OFF_SSRC);
  float* invd  = (float*)(ws + OFF_INVD);

  float* out_h  = (float*)d_out;
  float* out_hg = out_h + (size_t)NN * OUT;

  hipMemsetAsync(deg,  0, (size_t)NN * 4, stream);
  hipMemsetAsync(out_hg, 0, (size_t)NG * OUT * 4, stream);

  // CSR by dst
  k_deg    <<<(NE + 255) / 256, 256, 0, stream>>>(edst, deg);
  k_scan   <<<1, 1024, 0, stream>>>(deg, rp, cur, invd);
  k_scatter<<<(NE + 255) / 256, 256, 0, stream>>>(esrc, edst, cur, ssrc);

  // weights -> bf16 B^T (single fused dispatch)
  k_wconv_all<<<(WCT + 255) / 256, 256, 0, stream>>>(Ws0, Wn0, Ws1, Wn1, Ws2, Wn2,
                                                     Bt0, Bt1, BtSN2);

  // layer 0: A0 = [f | agg(f)], h0 = relu(A0 @ [Ws0;Wn0] + b0) -> A1[:, :512]
  k_build_A0<<<MPAD, 64, 0, stream>>>(feature, rp, ssrc, invd, A0);
  k_gemm<<<dim3(MT, 4), 256, 0, stream>>>(A0, 64, Bt0, 64, A1, 1024, b0, 1);

  // layer 1: agg(h0) -> A1[:, 512:], h1 = relu(A1 @ [Ws1;Wn1] + b1) -> A2[:, :512]
  k_agg512<<<NN, 128, 0, stream>>>(A1, rp, ssrc, invd);
  k_gemm<<<dim3(MT, 4), 256, 0, stream>>>(A1, 1024, Bt1, 1024, A2, 1024, b1, 1);

  // layer 2 (fused by linearity): agg(h1) -> A2[:, 512:],
  // out = A2 @ [Ws2;Wn2] + b2   (== h1@Ws2 + mean_agg(h1)@Wn2 + b2)
  k_agg512<<<NN, 128, 0, stream>>>(A2, rp, ssrc, invd);
  k_gemm<<<dim3(MT, 2), 256, 0, stream>>>(A2, 1024, BtSN2, 1024, out_h, 256, b2, 2);

  // avg pooling per graph (graph_ids sorted -> in-kernel binary search)
  k_pool<<<NG * 8, 256, 0, stream>>>(out_h, gid, out_hg);
}

// Round 7
// 313.223 us; speedup vs baseline: 1.4820x; 1.0017x over previous
//
#include <hip/hip_runtime.h>

// ---------------- problem constants ----------------
constexpr int NN   = 20000;   // nodes
constexpr int NE   = 160000;  // edges
constexpr int NG   = 32;      // graphs
constexpr int IN   = 27;
constexpr int HID  = 512;
constexpr int OUT  = 256;
constexpr int MPAD = 20096;   // 157 * 128
constexpr int MT   = MPAD / 128; // 157 m-tiles

typedef unsigned short u16;
typedef __bf16 bf16x8 __attribute__((ext_vector_type(8)));
typedef float  f32x4  __attribute__((ext_vector_type(4)));
typedef u16    u16x4  __attribute__((ext_vector_type(4)));

__device__ __forceinline__ u16 f2b(float x) {
  __bf16 h = (__bf16)x;                 // RNE convert
  return __builtin_bit_cast(u16, h);
}
__device__ __forceinline__ float b2f(u16 u) {
  __bf16 h = __builtin_bit_cast(__bf16, u);
  return (float)h;
}

#define GLOBAL_AS __attribute__((address_space(1)))
#define LDS_AS    __attribute__((address_space(3)))
__device__ __forceinline__ void gload_lds16(const void* g, void* l) {
  __builtin_amdgcn_global_load_lds((const GLOBAL_AS void*)g, (LDS_AS void*)l, 16, 0, 0);
}

// ---------------- CSR build ----------------
__global__ void k_deg(const int* __restrict__ dst, int* __restrict__ deg) {
  int e = blockIdx.x * 256 + threadIdx.x;
  if (e < NE) atomicAdd(&deg[dst[e]], 1);
}

// single-block scan; coalesced LDS stage + thread-serial chunks + wave shuffle scan
__global__ void k_scan(const int* __restrict__ deg, int* __restrict__ rowptr,
                       int* __restrict__ cursor, float* __restrict__ invdeg) {
  constexpr int CH = 20;                 // 1024 * 20 = 20480 >= NN
  __shared__ int sdeg[1024 * CH];
  __shared__ int wsum[16];
  const int tid = threadIdx.x;
  // coalesced global -> LDS
  for (int j = tid; j < 1024 * CH; j += 1024) sdeg[j] = (j < NN) ? deg[j] : 0;
  __syncthreads();
  const int i0 = tid * CH;
  int loc[CH];
  int sum = 0;
#pragma unroll
  for (int j = 0; j < CH; ++j) { loc[j] = sum; sum += sdeg[i0 + j]; }
  const int lane = tid & 63, wv = tid >> 6;
  int incl = sum;                        // wave-inclusive scan of chunk sums
#pragma unroll
  for (int off = 1; off < 64; off <<= 1) {
    int n = __shfl_up(incl, off);
    if (lane >= off) incl += n;
  }
  if (lane == 63) wsum[wv] = incl;
  __syncthreads();
  if (tid == 0) {
    int s = 0;
#pragma unroll
    for (int w = 0; w < 16; ++w) { int v = wsum[w]; wsum[w] = s + v; s += v; }
  }
  __syncthreads();
  const int wbase = (wv == 0) ? 0 : wsum[wv - 1];
  const int tbase = wbase + incl - sum;  // exclusive prefix of this chunk
#pragma unroll
  for (int j = 0; j < CH; ++j) {
    const int i = i0 + j;
    if (i < NN) {
      const int excl = tbase + loc[j];
      const int d = sdeg[i];
      rowptr[i] = excl;
      cursor[i] = excl;
      invdeg[i] = 1.0f / fmaxf((float)d, 1.0f);
    }
  }
  if (tid == 0) rowptr[NN] = wsum[15];
}

__global__ void k_scatter(const int* __restrict__ src, const int* __restrict__ dst,
                          int* __restrict__ cursor, int* __restrict__ ssrc) {
  int e = blockIdx.x * 256 + threadIdx.x;
  if (e < NE) {
    int p = atomicAdd(&cursor[dst[e]], 1);
    ssrc[p] = src[e];
  }
}

// ---------------- fused weight convert: all fp32 W -> bf16 B^T buffers in one dispatch
constexpr int WC0 = 512 * 64;     // Bt0 elems   [512][64]   <- [Ws0;Wn0] padded
constexpr int WC1 = 512 * 1024;   // Bt1 elems   [512][1024] <- [Ws1;Wn1]
constexpr int WC2 = 256 * 1024;   // BtSN2 elems [256][1024] <- [Ws2;Wn2]
constexpr int WCT = WC0 + WC1 + WC2;
__global__ void k_wconv_all(const float* __restrict__ Ws0, const float* __restrict__ Wn0,
                            const float* __restrict__ Ws1, const float* __restrict__ Wn1,
                            const float* __restrict__ Ws2, const float* __restrict__ Wn2,
                            u16* __restrict__ Bt0, u16* __restrict__ Bt1,
                            u16* __restrict__ BtSN2) {
  int idx = blockIdx.x * 256 + threadIdx.x;
  if (idx < WC0) {
    const int n = idx / 64, k = idx % 64;
    float v = 0.0f;
    if (k < IN)           v = Ws0[(size_t)k * 512 + n];
    else if (k < 2 * IN)  v = Wn0[(size_t)(k - IN) * 512 + n];
    Bt0[idx] = f2b(v);
    return;
  }
  idx -= WC0;
  if (idx < WC1) {
    const int n = idx / 1024, k = idx % 1024;
    const float v = (k < 512) ? Ws1[(size_t)k * 512 + n] : Wn1[(size_t)(k - 512) * 512 + n];
    Bt1[idx] = f2b(v);
    return;
  }
  idx -= WC1;
  if (idx < WC2) {
    const int n = idx / 1024, k = idx % 1024;
    const float v = (k < 512) ? Ws2[(size_t)k * 256 + n] : Wn2[(size_t)(k - 512) * 256 + n];
    BtSN2[idx] = f2b(v);
  }
}

// ---------------- A0 = [bf16(feature) | bf16(mean-agg(feature)) | zeros], [MPAD][64]
__global__ void k_build_A0(const float* __restrict__ feat, const int* __restrict__ rowptr,
                           const int* __restrict__ ssrc, const float* __restrict__ invdeg,
                           u16* __restrict__ A0) {
  const int r = blockIdx.x, t = threadIdx.x; // 64 threads
  u16* row = A0 + (size_t)r * 64;
  if (r >= NN) { row[t] = 0; return; }
  if (t < IN) {
    row[t] = f2b(feat[(size_t)r * IN + t]);
    float s = 0.0f;
    const int e0 = rowptr[r], e1 = rowptr[r + 1];
    for (int e = e0; e < e1; ++e) s += feat[(size_t)ssrc[e] * IN + t];
    row[IN + t] = f2b(s * invdeg[r]);
  } else if (t >= 2 * IN) {
    row[t] = 0;
  }
}

// ---------------- agg over cols [0,512) of X[MPAD][1024] -> cols [512,1024)
__global__ void k_agg512(u16* __restrict__ X, const int* __restrict__ rowptr,
                         const int* __restrict__ ssrc, const float* __restrict__ invdeg) {
  const int r = blockIdx.x, t = threadIdx.x; // 128 threads, 4 cols each
  float a0 = 0, a1 = 0, a2 = 0, a3 = 0;
  const int e0 = rowptr[r], e1 = rowptr[r + 1];
  for (int e = e0; e < e1; ++e) {
    const u16x4 v = *(const u16x4*)(X + (size_t)ssrc[e] * 1024 + t * 4);
    a0 += b2f(v.x); a1 += b2f(v.y); a2 += b2f(v.z); a3 += b2f(v.w);
  }
  const float inv = invdeg[r];
  u16x4 o; o.x = f2b(a0 * inv); o.y = f2b(a1 * inv); o.z = f2b(a2 * inv); o.w = f2b(a3 * inv);
  *(u16x4*)(X + (size_t)r * 1024 + 512 + t * 4) = o;
}

// ---------------- MFMA GEMM: D = A[MPAD][lda](bf16) x Bt[Nout][K](bf16)^T tiles 128x128
// 1-D grid of MT*nt blocks, XCD-grouped swizzle: blocks congruent mod 8 enumerate the
// col-tiles of one M-tile, so one XCD's L2 reuses the A-tile across all nt col-tiles.
// flags: 1 = relu (bf16 out), 2 = fp32 out to d_out with row<NN guard
__global__ __launch_bounds__(256) void k_gemm(
    const u16* __restrict__ A, int lda,
    const u16* __restrict__ Bt, int K,
    void* __restrict__ Out, int ldo,
    const float* __restrict__ bias,
    int flags, int nt) {
  __shared__ u16 As[128 * 64];
  __shared__ u16 Bs[128 * 64];
  const int tid = threadIdx.x;
  const int wid = tid >> 6, lane = tid & 63;
  const int l16 = lane & 15, lhi = lane >> 4;
  const int wr = wid >> 1, wc = wid & 1;

  // ---- XCD-grouped tile mapping (bijective; nt is a power of two) ----
  const int G    = gridDim.x;
  const int PER  = nt * 8;
  const int nOct = G / PER;              // full 8-Mtile groups
  const int base = nOct * PER;
  int x, y;
  if ((int)blockIdx.x < base) {
    x = (blockIdx.x & 7) + 8 * (blockIdx.x / PER);
    y = (blockIdx.x >> 3) & (nt - 1);
  } else {
    const int j = blockIdx.x - base;
    x = 8 * nOct + j / nt;
    y = j - (j / nt) * nt;
  }
  const int row0 = x * 128, col0 = y * 128;

  // staging decomposition: each thread owns one 16B slot; swizzle the GLOBAL
  // source slot so a swizzled ds_read_b128 sees linear data (rule 21)
  const int tr    = tid >> 3;              // row within 32-row issue
  const int slot  = tid & 7;               // 16B slot within 128B row
  const int sslot = slot ^ (tr & 7);       // inverse-swizzled source slot

  f32x4 acc[4][4] = {};

  for (int kt = 0; kt < K; kt += 64) {
#pragma unroll
    for (int i = 0; i < 4; ++i) {
      const int r = i * 32 + tr;
      gload_lds16(A  + (size_t)(row0 + r) * lda + kt + sslot * 8, &As[i * 2048 + wid * 512]);
      gload_lds16(Bt + (size_t)(col0 + r) * K   + kt + sslot * 8, &Bs[i * 2048 + wid * 512]);
    }
    __syncthreads();
#pragma unroll
    for (int ks = 0; ks < 2; ++ks) {
      bf16x8 af[4], bfr[4];
#pragma unroll
      for (int i = 0; i < 4; ++i) {
        const int r = wr * 64 + i * 16 + l16;
        const int s = (ks * 4 + lhi) ^ (r & 7);
        af[i] = *(const bf16x8*)&As[r * 64 + s * 8];
      }
#pragma unroll
      for (int n = 0; n < 4; ++n) {
        const int c = wc * 64 + n * 16 + l16;
        const int s = (ks * 4 + lhi) ^ (c & 7);
        bfr[n] = *(const bf16x8*)&Bs[c * 64 + s * 8];
      }
#pragma unroll
      for (int i = 0; i < 4; ++i)
#pragma unroll
        for (int n = 0; n < 4; ++n)
          acc[i][n] = __builtin_amdgcn_mfma_f32_16x16x32_bf16(af[i], bfr[n], acc[i][n], 0, 0, 0);
    }
    __syncthreads();
  }

  const bool relu = flags & 1;
  const bool f32o = flags & 2;
#pragma unroll
  for (int i = 0; i < 4; ++i) {
#pragma unroll
    for (int n = 0; n < 4; ++n) {
      const int C = col0 + wc * 64 + n * 16 + l16;
      const float bv = bias ? bias[C] : 0.0f;
#pragma unroll
      for (int q = 0; q < 4; ++q) {
        const int R = row0 + wr * 64 + i * 16 + lhi * 4 + q;
        float v = acc[i][n][q] + bv;
        if (f32o) {
          if (R < NN) ((float*)Out)[(size_t)R * ldo + C] = v;
        } else {
          if (relu) v = fmaxf(v, 0.0f);
          ((u16*)Out)[(size_t)R * ldo + C] = f2b(v);
        }
      }
    }
  }
}

// ---------------- pooling (graph_ids sorted; binary search in-kernel) ----------------
__device__ __forceinline__ int lower_bound_g(const int* __restrict__ gid, int g) {
  int lo = 0, hi = NN;
  while (lo < hi) {
    const int mid = (lo + hi) >> 1;
    if (gid[mid] < g) lo = mid + 1; else hi = mid;
  }
  return lo;
}
// partial sums pre-scaled by 1/count -> no separate divide pass
__global__ void k_pool(const float* __restrict__ h, const int* __restrict__ gid,
                       float* __restrict__ hg) {
  __shared__ int s_n0, s_n1;
  const int g = blockIdx.x >> 3, s = blockIdx.x & 7;
  const int t = threadIdx.x; // 256 = output col
  if (t == 0) { s_n0 = lower_bound_g(gid, g); s_n1 = lower_bound_g(gid, g + 1); }
  __syncthreads();
  const int n0 = s_n0, n1 = s_n1;
  const int len = n1 - n0, chunk = (len + 7) / 8;
  const int a = n0 + s * chunk;
  const int b = min(a + chunk, n1);
  float acc = 0.0f;
  for (int i = a; i < b; ++i) acc += h[(size_t)i * 256 + t];
  if (b > a) {
    const float inv = 1.0f / fmaxf((float)len, 1.0f);
    atomicAdd(&hg[g * 256 + t], acc * inv);
  }
}

// ---------------- workspace layout (bytes) ----------------
constexpr size_t OFF_A0    = 0;                                   // [MPAD][64] bf16
constexpr size_t OFF_A1    = OFF_A0   + (size_t)MPAD * 64  * 2;   // [MPAD][1024] bf16 (h0|agg h0)
constexpr size_t OFF_A2    = OFF_A1   + (size_t)MPAD * 1024 * 2;  // [MPAD][1024] bf16 (h1|agg h1)
constexpr size_t OFF_BT0   = OFF_A2   + (size_t)MPAD * 1024 * 2;  // [512][64] bf16
constexpr size_t OFF_BT1   = OFF_BT0  + (size_t)512 * 64 * 2;     // [512][1024] bf16
constexpr size_t OFF_BTSN2 = OFF_BT1  + (size_t)512 * 1024 * 2;   // [256][1024] bf16
constexpr size_t OFF_DEG   = OFF_BTSN2+ (size_t)256 * 1024 * 2;   // [NN] int
constexpr size_t OFF_RP    = OFF_DEG  + (size_t)NN * 4;           // [NN+1] int
constexpr size_t OFF_CUR   = OFF_RP   + (size_t)(NN + 2) * 4;     // [NN] int
constexpr size_t OFF_SSRC  = OFF_CUR  + (size_t)NN * 4;           // [NE] int
constexpr size_t OFF_INVD  = OFF_SSRC + (size_t)NE * 4;           // [NN] float

extern "C" void kernel_launch(void* const* d_in, const int* in_sizes, int n_in,
                              void* d_out, int out_size, void* d_ws, size_t ws_size,
                              hipStream_t stream) {
  const float* feature = (const float*)d_in[0];
  const int*   esrc    = (const int*)d_in[1];
  const int*   edst    = (const int*)d_in[2];
  const int*   gid     = (const int*)d_in[3];
  const float* Ws0 = (const float*)d_in[4],  *Wn0 = (const float*)d_in[5],  *b0 = (const float*)d_in[6];
  const float* Ws1 = (const float*)d_in[7],  *Wn1 = (const float*)d_in[8],  *b1 = (const float*)d_in[9];
  const float* Ws2 = (const float*)d_in[10], *Wn2 = (const float*)d_in[11], *b2 = (const float*)d_in[12];

  char* ws = (char*)d_ws;
  u16*   A0    = (u16*)  (ws + OFF_A0);
  u16*   A1    = (u16*)  (ws + OFF_A1);
  u16*   A2    = (u16*)  (ws + OFF_A2);
  u16*   Bt0   = (u16*)  (ws + OFF_BT0);
  u16*   Bt1   = (u16*)  (ws + OFF_BT1);
  u16*   BtSN2 = (u16*)  (ws + OFF_BTSN2);
  int*   deg   = (int*)  (ws + OFF_DEG);
  int*   rp    = (int*)  (ws + OFF_RP);
  int*   cur   = (int*)  (ws + OFF_CUR);
  int*   ssrc  = (int*)  (ws + OFF_SSRC);
  float* invd  = (float*)(ws + OFF_INVD);

  float* out_h  = (float*)d_out;
  float* out_hg = out_h + (size_t)NN * OUT;

  hipMemsetAsync(deg,  0, (size_t)NN * 4, stream);
  hipMemsetAsync(out_hg, 0, (size_t)NG * OUT * 4, stream);

  // CSR by dst
  k_deg    <<<(NE + 255) / 256, 256, 0, stream>>>(edst, deg);
  k_scan   <<<1, 1024, 0, stream>>>(deg, rp, cur, invd);
  k_scatter<<<(NE + 255) / 256, 256, 0, stream>>>(esrc, edst, cur, ssrc);

  // weights -> bf16 B^T (single fused dispatch)
  k_wconv_all<<<(WCT + 255) / 256, 256, 0, stream>>>(Ws0, Wn0, Ws1, Wn1, Ws2, Wn2,
                                                     Bt0, Bt1, BtSN2);

  // layer 0: A0 = [f | agg(f)], h0 = relu(A0 @ [Ws0;Wn0] + b0) -> A1[:, :512]
  k_build_A0<<<MPAD, 64, 0, stream>>>(feature, rp, ssrc, invd, A0);
  k_gemm<<<MT * 4, 256, 0, stream>>>(A0, 64, Bt0, 64, A1, 1024, b0, 1, 4);

  // layer 1: agg(h0) -> A1[:, 512:], h1 = relu(A1 @ [Ws1;Wn1] + b1) -> A2[:, :512]
  k_agg512<<<NN, 128, 0, stream>>>(A1, rp, ssrc, invd);
  k_gemm<<<MT * 4, 256, 0, stream>>>(A1, 1024, Bt1, 1024, A2, 1024, b1, 1, 4);

  // layer 2 (fused by linearity): agg(h1) -> A2[:, 512:],
  // out = A2 @ [Ws2;Wn2] + b2   (== h1@Ws2 + mean_agg(h1)@Wn2 + b2)
  k_agg512<<<NN, 128, 0, stream>>>(A2, rp, ssrc, invd);
  k_gemm<<<MT * 2, 256, 0, stream>>>(A2, 1024, BtSN2, 1024, out_h, 256, b2, 2, 2);

  // avg pooling per graph (graph_ids sorted -> in-kernel binary search)
  k_pool<<<NG * 8, 256, 0, stream>>>(out_h, gid, out_hg);
}